// Round 8
// baseline (415.406 us; speedup 1.0000x reference)
//
#include <hip/hip_runtime.h>
#include <hip/hip_bf16.h>

#define NN 100000
#define F 128
#define C_OUT 14
#define ZP 16
#define WIN 64
#define NWIN ((NN + WIN - 1) / WIN)    // 1563 windows of 64 nodes
#define WCAP 1408                      // mean 1024, +12 sigma
#define EBATCH 4096
#define HS 136                         // hsm/W2s stride (shorts): 16B-aligned
#define WPREPB 144                     // wprep item blocks (36864/256)

typedef __attribute__((ext_vector_type(8))) short v8s;   // 8 bf16 (4 VGPRs)
typedef __attribute__((ext_vector_type(4))) float v4f;   // 4 fp32 acc
typedef __attribute__((ext_vector_type(2))) float v2f;   // 2 fp32 (cvt_pk result)

// ---------------- bf16 helpers ----------------------------------------------
static __device__ __forceinline__ unsigned short f2bf(float f) {
    unsigned int u = __float_as_uint(f);
    unsigned int r = (u + 0x7fffu + ((u >> 16) & 1u)) >> 16;   // RTN-even
    return (unsigned short)r;
}
static __device__ __forceinline__ unsigned int pack2(float a, float b) {
    return (unsigned int)f2bf(a) | ((unsigned int)f2bf(b) << 16);
}
static __device__ __forceinline__ void unpack2(unsigned int u, float& lo, float& hi) {
    lo = __uint_as_float(u << 16);
    hi = __uint_as_float(u & 0xffff0000u);
}
// 8 fp8 (uint2) -> accumulate into a[8] via HW converters (2 elems/inst)
static __device__ __forceinline__ void accf8(const uint2 u, float* a) {
    v2f f0 = __builtin_amdgcn_cvt_pk_f32_fp8((int)u.x, false);
    a[0] += f0[0]; a[1] += f0[1];
    v2f f1 = __builtin_amdgcn_cvt_pk_f32_fp8((int)u.x, true);
    a[2] += f1[0]; a[3] += f1[1];
    v2f f2 = __builtin_amdgcn_cvt_pk_f32_fp8((int)u.y, false);
    a[4] += f2[0]; a[5] += f2[1];
    v2f f3 = __builtin_amdgcn_cvt_pk_f32_fp8((int)u.y, true);
    a[6] += f3[0]; a[7] += f3[1];
}
// 4 consecutive bf16 (LDS) -> 4 fp8 packed in one word
static __device__ __forceinline__ unsigned int bf4_to_fp8x4(const unsigned short* sp) {
    float f0, f1, f2, f3;
    unpack2(*(const unsigned int*)(sp + 0), f0, f1);
    unpack2(*(const unsigned int*)(sp + 2), f2, f3);
    unsigned int w = __builtin_amdgcn_cvt_pk_fp8_f32(f0, f1, 0, false);
    return __builtin_amdgcn_cvt_pk_fp8_f32(f2, f3, w, true);
}

// ---------------------------------------------------------------------------
// prepA: per-dst degree count (global atomics) + wprep roles.
// ---------------------------------------------------------------------------
__global__ __launch_bounds__(256) void prepA_kernel(
    const int* __restrict__ dst, int* __restrict__ dcnt, int E, int binBlocks,
    const float* __restrict__ W1l, const float* __restrict__ W1r,
    const float* __restrict__ W2l, const float* __restrict__ W2r,
    unsigned short* __restrict__ Wb, unsigned short* __restrict__ W2t)
{
    const int t = threadIdx.x;
    if ((int)blockIdx.x >= binBlocks) {
        const int idx = ((int)blockIdx.x - binBlocks) * 256 + t;
        if (idx < 2 * 128 * 128) {
            const int c   = idx >> 14;
            const int rem = idx & 16383;
            const int n   = rem >> 7;
            const int k   = rem & 127;
            const float* W = c ? W1r : W1l;
            Wb[idx] = f2bf(W[k * 128 + n]);
        } else if (idx < 2 * 128 * 128 + 32 * 128) {
            const int j = idx - 2 * 128 * 128;
            const int n = j >> 7;
            const int k = j & 127;
            float wv = 0.0f;
            if (n < 16) { if (n < C_OUT) wv = W2l[k * C_OUT + n]; }
            else        { if (n - 16 < C_OUT) wv = W2r[k * C_OUT + (n - 16)]; }
            W2t[j] = f2bf(wv);
        }
        return;
    }
    const int e0 = blockIdx.x * EBATCH;
    #pragma unroll
    for (int j = 0; j < 16; ++j) {
        const int e = e0 + j * 256 + t;
        if (e < E) atomicAdd(&dcnt[dst[e]], 1);
    }
}

// ---------------------------------------------------------------------------
// scan: per-window exclusive scan of 64 degree counts (one wave per window)
// -> absolute gbase[n] (clamped at WCAP) and scatter cursors ncur[n].
// ---------------------------------------------------------------------------
__global__ __launch_bounds__(256) void scan_kernel(
    const int* __restrict__ dcnt, int* __restrict__ gbase, int* __restrict__ ncur)
{
    const int t    = threadIdx.x;
    const int widx = blockIdx.x * 4 + (t >> 6);
    if (widx >= NWIN) return;
    const int lane = t & 63;
    const int n    = widx * WIN + lane;
    const int c    = dcnt[n];
    int v = c;
    #pragma unroll
    for (int off = 1; off < WIN; off <<= 1) {
        const int u = __shfl_up(v, off, WIN);
        if (lane >= off) v += u;
    }
    const int ex = v - c;                       // exclusive prefix
    const int b  = widx * WCAP + min(ex, WCAP); // absolute, clamped
    gbase[n] = b;
    ncur[n]  = b;
}

// ---------------------------------------------------------------------------
// prepB: scatter edges to their exact sorted slot -> bucket is born sorted.
// ---------------------------------------------------------------------------
__global__ __launch_bounds__(256) void prepB_kernel(
    const int* __restrict__ src, const int* __restrict__ dst,
    int* __restrict__ ncur, unsigned* __restrict__ bucket, int E)
{
    const int e0 = blockIdx.x * EBATCH;
    #pragma unroll
    for (int j = 0; j < 16; ++j) {
        const int e = e0 + j * 256 + threadIdx.x;
        if (e < E) {
            const int d = dst[e];
            const int pos = atomicAdd(&ncur[d], 1);
            if (pos < (d >> 6) * WCAP + WCAP)   // window-overflow drop (never in practice)
                bucket[pos] = (unsigned)src[e];
        }
    }
}

// ---------------------------------------------------------------------------
// pre1 (MFMA): pqa = fp8 of x@W1l [NN][128], pqs = bf16 of x@W1r + b1 [NN][128].
// (unchanged from R14)
// ---------------------------------------------------------------------------
#define KSA 136
__global__ __launch_bounds__(256, 3) void pre1_kernel(
    const float* __restrict__ x, const unsigned short* __restrict__ Wb,
    const float* __restrict__ b1, unsigned char* __restrict__ pqa,
    unsigned short* __restrict__ pqs)
{
    __shared__ unsigned short A_s[64 * KSA];   // 17408 B (reused as C_s)

    const int t    = threadIdx.x;
    const int m0   = blockIdx.x * 64;
    const int lane = t & 63;
    const int wave = t >> 6;
    const int lr   = lane & 15;
    const int quad = lane >> 4;
    const int nw0  = wave * 64;

    v8s bf[4][4];
    #pragma unroll
    for (int nt = 0; nt < 4; ++nt)
        #pragma unroll
        for (int ks = 0; ks < 4; ++ks)
            bf[nt][ks] = *(const v8s*)(Wb + (size_t)(nw0 + nt * 16 + lr) * 128 + ks * 32 + quad * 8);

    {
        const int mi = t & 63;
        const int ko = (t >> 6) * 32;
        const int m  = m0 + mi;
        unsigned short* dp = &A_s[mi * KSA + ko];
        if (m < NN) {
            const float4* sp = (const float4*)(x + (size_t)m * F + ko);
            #pragma unroll
            for (int j = 0; j < 8; j += 2) {
                const float4 f0 = sp[j], f1 = sp[j + 1];
                uint4 o;
                o.x = pack2(f0.x, f0.y); o.y = pack2(f0.z, f0.w);
                o.z = pack2(f1.x, f1.y); o.w = pack2(f1.z, f1.w);
                *(uint4*)(dp + j * 4) = o;
            }
        } else {
            #pragma unroll
            for (int j = 0; j < 4; ++j)
                *(uint4*)(dp + j * 8) = make_uint4(0u, 0u, 0u, 0u);
        }
    }
    __syncthreads();

    v4f acc[4][4];
    #pragma unroll
    for (int mt = 0; mt < 4; ++mt)
        #pragma unroll
        for (int nt = 0; nt < 4; ++nt)
            acc[mt][nt] = (v4f){0.f, 0.f, 0.f, 0.f};

    #pragma unroll
    for (int ks = 0; ks < 4; ++ks) {
        const int k0 = ks * 32 + quad * 8;
        #pragma unroll
        for (int mt = 0; mt < 4; ++mt) {
            const v8s a = *(const v8s*)&A_s[(mt * 16 + lr) * KSA + k0];
            acc[mt][0] = __builtin_amdgcn_mfma_f32_16x16x32_bf16(a, bf[0][ks], acc[mt][0], 0, 0, 0);
            acc[mt][1] = __builtin_amdgcn_mfma_f32_16x16x32_bf16(a, bf[1][ks], acc[mt][1], 0, 0, 0);
            acc[mt][2] = __builtin_amdgcn_mfma_f32_16x16x32_bf16(a, bf[2][ks], acc[mt][2], 0, 0, 0);
            acc[mt][3] = __builtin_amdgcn_mfma_f32_16x16x32_bf16(a, bf[3][ks], acc[mt][3], 0, 0, 0);
        }
    }
    __syncthreads();

    float bias[4];
    #pragma unroll
    for (int nt = 0; nt < 4; ++nt) {
        const int n = nw0 + nt * 16 + lr;
        bias[nt] = (n >= 128) ? b1[n - 128] : 0.0f;
    }

    unsigned short* C_s = A_s;
    #pragma unroll
    for (int p = 0; p < 2; ++p) {
        if ((nw0 >> 7) == p) {
            #pragma unroll
            for (int mt = 0; mt < 4; ++mt)
                #pragma unroll
                for (int nt = 0; nt < 4; ++nt) {
                    const int n = (nw0 & 127) + nt * 16 + lr;
                    #pragma unroll
                    for (int r = 0; r < 4; ++r) {
                        const int m = mt * 16 + quad * 4 + r;
                        C_s[m * KSA + n] = f2bf(acc[mt][nt][r] + bias[nt]);
                    }
                }
        }
        __syncthreads();
        if (p == 0) {
            const int mi8 = t >> 2;
            const int c0  = (t & 3) * 32;
            const int m   = m0 + mi8;
            if (m < NN) {
                unsigned char* dp = pqa + (size_t)m * 128 + c0;
                #pragma unroll
                for (int j = 0; j < 2; ++j) {
                    const unsigned short* sp = &C_s[mi8 * KSA + c0 + j * 16];
                    uint4 w;
                    w.x = bf4_to_fp8x4(sp + 0);
                    w.y = bf4_to_fp8x4(sp + 4);
                    w.z = bf4_to_fp8x4(sp + 8);
                    w.w = bf4_to_fp8x4(sp + 12);
                    *(uint4*)(dp + j * 16) = w;
                }
            }
        } else {
            const int mi = t >> 2;
            const int c0 = (t & 3) * 32;
            const int m  = m0 + mi;
            if (m < NN) {
                unsigned short* dp = pqs + (size_t)m * 128 + c0;
                const unsigned short* sp = &C_s[mi * KSA + c0];
                #pragma unroll
                for (int j = 0; j < 4; ++j)
                    *(uint4*)(dp + j * 8) = *(const uint4*)(sp + j * 8);
            }
        }
        __syncthreads();
    }
}

// ---------------------------------------------------------------------------
// agg1f: consumes the PRE-SORTED bucket -- sort prologue DELETED (R16).
// Prologue = load 64 base/len + one coalesced slice copy. fp8 gather + fused
// pre2 (MFMA) unchanged. LDS 32256 -> 5 blocks/CU.
// ---------------------------------------------------------------------------
#define ISSUE8(U, B) { \
    const int s0_=(int)lp[(B)+0], s1_=(int)lp[(B)+1], s2_=(int)lp[(B)+2], s3_=(int)lp[(B)+3], \
              s4_=(int)lp[(B)+4], s5_=(int)lp[(B)+5], s6_=(int)lp[(B)+6], s7_=(int)lp[(B)+7]; \
    U##0=*(const uint2*)(pqa+(size_t)s0_*128+col); U##1=*(const uint2*)(pqa+(size_t)s1_*128+col); \
    U##2=*(const uint2*)(pqa+(size_t)s2_*128+col); U##3=*(const uint2*)(pqa+(size_t)s3_*128+col); \
    U##4=*(const uint2*)(pqa+(size_t)s4_*128+col); U##5=*(const uint2*)(pqa+(size_t)s5_*128+col); \
    U##6=*(const uint2*)(pqa+(size_t)s6_*128+col); U##7=*(const uint2*)(pqa+(size_t)s7_*128+col); }
#define PROC8(U) { accf8(U##0,a0); accf8(U##1,a1); accf8(U##2,a2); accf8(U##3,a3); \
                   accf8(U##4,a0); accf8(U##5,a1); accf8(U##6,a2); accf8(U##7,a3); }

__global__ __launch_bounds__(256, 5) void agg1f_kernel(
    const unsigned char* __restrict__ pqa, const unsigned short* __restrict__ pqs,
    const unsigned* __restrict__ bucket, const int* __restrict__ gbase,
    const int* __restrict__ dcnt, const unsigned short* __restrict__ W2t,
    const float* __restrict__ b2, unsigned short* __restrict__ z, float* __restrict__ r)
{
    __shared__ unsigned list[WCAP];                 // 5632 B
    __shared__ int base_s[WIN], cnt_s[WIN];         // 512 B
    __shared__ unsigned short hsm[WIN * HS];        // 17408 B
    __shared__ unsigned short W2s[32 * HS];         // 8704 B   (total 32256)
    const int t  = threadIdx.x;
    const int wb = blockIdx.x;
    const unsigned* bp = bucket + (size_t)wb * WCAP;

    {
        const int row = t >> 3;
        const int c16 = (t & 7) * 16;
        *(uint4*)&W2s[row * HS + c16]     = *(const uint4*)&W2t[row * 128 + c16];
        *(uint4*)&W2s[row * HS + c16 + 8] = *(const uint4*)&W2t[row * 128 + c16 + 8];
    }
    if (t < WIN) {
        const int n    = wb * WIN + t;
        const int brel = gbase[n] - wb * WCAP;      // 0..WCAP
        base_s[t] = brel;
        cnt_s[t]  = min(dcnt[n], WCAP - brel);
    }
    for (int i = t; i < WCAP; i += 256) list[i] = bp[i];
    __syncthreads();

    const int g    = t >> 4;      // 16 groups
    const int lane = t & 15;
    const int col  = lane * 8;    // byte offset into the 128B fp8 row
    #pragma unroll
    for (int rep = 0; rep < 4; ++rep) {
        const int nloc = rep * 16 + g;
        const int n = wb * WIN + nloc;
        if (n >= NN) continue;
        const int start = base_s[nloc];
        const int len   = cnt_s[nloc];
        float a0[8] = {0,0,0,0,0,0,0,0};
        float a1[8] = {0,0,0,0,0,0,0,0};
        float a2[8] = {0,0,0,0,0,0,0,0};
        float a3[8] = {0,0,0,0,0,0,0,0};
        const unsigned* lp = list + start;
        uint2 uA0,uA1,uA2,uA3,uA4,uA5,uA6,uA7;
        uint2 uB0,uB1,uB2,uB3,uB4,uB5,uB6,uB7;
        int i = 0;
        if (len >= 8) ISSUE8(uA, 0);
        for (; i + 24 <= len; i += 16) {
            ISSUE8(uB, i + 8);
            PROC8(uA);
            ISSUE8(uA, i + 16);
            PROC8(uB);
        }
        if (i + 16 <= len) {
            ISSUE8(uB, i + 8);
            PROC8(uA);
            PROC8(uB);
            i += 16;
        } else if (i + 8 <= len) {
            PROC8(uA);
            i += 8;
        }
        for (; i + 4 <= len; i += 4) {
            const int s0 = (int)lp[i + 0];
            const int s1 = (int)lp[i + 1];
            const int s2 = (int)lp[i + 2];
            const int s3 = (int)lp[i + 3];
            const uint2 u0 = *(const uint2*)(pqa + (size_t)s0 * 128 + col);
            const uint2 u1 = *(const uint2*)(pqa + (size_t)s1 * 128 + col);
            const uint2 u2 = *(const uint2*)(pqa + (size_t)s2 * 128 + col);
            const uint2 u3 = *(const uint2*)(pqa + (size_t)s3 * 128 + col);
            accf8(u0, a0); accf8(u1, a1); accf8(u2, a2); accf8(u3, a3);
        }
        for (; i < len; ++i) {
            const int s = (int)lp[i];
            const uint2 u = *(const uint2*)(pqa + (size_t)s * 128 + col);
            accf8(u, a0);
        }
        const float inv = 1.0f / (float)max(len, 1);
        const uint4 uq = *(const uint4*)(pqs + (size_t)n * 128 + lane * 8);
        float q[8];
        unpack2(uq.x, q[0], q[1]); unpack2(uq.y, q[2], q[3]);
        unpack2(uq.z, q[4], q[5]); unpack2(uq.w, q[6], q[7]);
        float hv[8];
        #pragma unroll
        for (int j = 0; j < 8; ++j)
            hv[j] = fmaxf((a0[j] + a1[j] + a2[j] + a3[j]) * inv + q[j], 0.0f);
        uint4 o;
        o.x = pack2(hv[0], hv[1]);
        o.y = pack2(hv[2], hv[3]);
        o.z = pack2(hv[4], hv[5]);
        o.w = pack2(hv[6], hv[7]);
        *(uint4*)&hsm[nloc * HS + lane * 8] = o;
    }
    __syncthreads();

    // fused pre2 via MFMA: [z|r](64x32) = h(64x128) @ W2t^T.
    {
        const int wave = t >> 6;
        const int l64  = t & 63;
        const int lr   = l64 & 15;
        const int quad = l64 >> 4;
        const int m0w  = wave * 16;
        v4f accz = (v4f){0.f, 0.f, 0.f, 0.f};
        v4f accr = (v4f){0.f, 0.f, 0.f, 0.f};
        #pragma unroll
        for (int kt = 0; kt < 4; ++kt) {
            const int k0 = kt * 32 + quad * 8;
            const v8s a  = *(const v8s*)&hsm[(m0w + lr) * HS + k0];
            const v8s bz = *(const v8s*)&W2s[lr * HS + k0];
            const v8s br = *(const v8s*)&W2s[(16 + lr) * HS + k0];
            accz = __builtin_amdgcn_mfma_f32_16x16x32_bf16(a, bz, accz, 0, 0, 0);
            accr = __builtin_amdgcn_mfma_f32_16x16x32_bf16(a, br, accr, 0, 0, 0);
        }
        const float b2v = (lr < C_OUT) ? b2[lr] : 0.0f;
        #pragma unroll
        for (int rr = 0; rr < 4; ++rr) {
            const int m = m0w + quad * 4 + rr;
            const int n = wb * WIN + m;
            if (n < NN) {
                z[(size_t)n * ZP + lr] = f2bf(accz[rr]);
                r[(size_t)n * ZP + lr] = accr[rr] + b2v;
            }
        }
    }
}

// ---------------------------------------------------------------------------
// agg2s: consumes the PRE-SORTED bucket (base/len from gbase/dcnt).
// ---------------------------------------------------------------------------
__global__ __launch_bounds__(256) void agg2s_kernel(
    const unsigned short* __restrict__ z, const float* __restrict__ r,
    const unsigned* __restrict__ bucket, const int* __restrict__ gbase,
    const int* __restrict__ dcnt, const int* __restrict__ sf_ptr,
    float* __restrict__ out)
{
    __shared__ unsigned list[WCAP];
    __shared__ int base_s[WIN], cnt_s[WIN];
    __shared__ float sm[WIN][ZP + 1];
    const int t  = threadIdx.x;
    const int wb = blockIdx.x;
    const unsigned* bp = bucket + (size_t)wb * WCAP;

    if (t < WIN) {
        const int n    = wb * WIN + t;
        const int brel = gbase[n] - wb * WCAP;
        base_s[t] = brel;
        cnt_s[t]  = min(dcnt[n], WCAP - brel);
    }
    for (int i = t; i < WCAP; i += 256) list[i] = bp[i];
    __syncthreads();

    const int g  = t >> 2;      // node slot 0..63
    const int j4 = (t & 3) * 4;
    const int n  = wb * WIN + g;
    if (n < NN) {
        const int start = base_s[g];
        const int len   = cnt_s[g];
        float4 a0 = make_float4(0.f, 0.f, 0.f, 0.f);
        float4 a1 = a0, a2 = a0, a3 = a0;
        int i = 0;
        for (; i + 8 <= len; i += 8) {
            const int s0 = (int)list[start + i + 0];
            const int s1 = (int)list[start + i + 1];
            const int s2 = (int)list[start + i + 2];
            const int s3 = (int)list[start + i + 3];
            const int s4 = (int)list[start + i + 4];
            const int s5 = (int)list[start + i + 5];
            const int s6 = (int)list[start + i + 6];
            const int s7 = (int)list[start + i + 7];
            const uint2 u0 = *(const uint2*)(z + (size_t)s0 * ZP + j4);
            const uint2 u1 = *(const uint2*)(z + (size_t)s1 * ZP + j4);
            const uint2 u2 = *(const uint2*)(z + (size_t)s2 * ZP + j4);
            const uint2 u3 = *(const uint2*)(z + (size_t)s3 * ZP + j4);
            const uint2 u4 = *(const uint2*)(z + (size_t)s4 * ZP + j4);
            const uint2 u5 = *(const uint2*)(z + (size_t)s5 * ZP + j4);
            const uint2 u6 = *(const uint2*)(z + (size_t)s6 * ZP + j4);
            const uint2 u7 = *(const uint2*)(z + (size_t)s7 * ZP + j4);
            float f0, f1, f2, f3;
            unpack2(u0.x, f0, f1); unpack2(u0.y, f2, f3);
            a0.x += f0; a0.y += f1; a0.z += f2; a0.w += f3;
            unpack2(u1.x, f0, f1); unpack2(u1.y, f2, f3);
            a1.x += f0; a1.y += f1; a1.z += f2; a1.w += f3;
            unpack2(u2.x, f0, f1); unpack2(u2.y, f2, f3);
            a2.x += f0; a2.y += f1; a2.z += f2; a2.w += f3;
            unpack2(u3.x, f0, f1); unpack2(u3.y, f2, f3);
            a3.x += f0; a3.y += f1; a3.z += f2; a3.w += f3;
            unpack2(u4.x, f0, f1); unpack2(u4.y, f2, f3);
            a0.x += f0; a0.y += f1; a0.z += f2; a0.w += f3;
            unpack2(u5.x, f0, f1); unpack2(u5.y, f2, f3);
            a1.x += f0; a1.y += f1; a1.z += f2; a1.w += f3;
            unpack2(u6.x, f0, f1); unpack2(u6.y, f2, f3);
            a2.x += f0; a2.y += f1; a2.z += f2; a2.w += f3;
            unpack2(u7.x, f0, f1); unpack2(u7.y, f2, f3);
            a3.x += f0; a3.y += f1; a3.z += f2; a3.w += f3;
        }
        for (; i + 4 <= len; i += 4) {
            const int s0 = (int)list[start + i + 0];
            const int s1 = (int)list[start + i + 1];
            const int s2 = (int)list[start + i + 2];
            const int s3 = (int)list[start + i + 3];
            const uint2 u0 = *(const uint2*)(z + (size_t)s0 * ZP + j4);
            const uint2 u1 = *(const uint2*)(z + (size_t)s1 * ZP + j4);
            const uint2 u2 = *(const uint2*)(z + (size_t)s2 * ZP + j4);
            const uint2 u3 = *(const uint2*)(z + (size_t)s3 * ZP + j4);
            float f0, f1, f2, f3;
            unpack2(u0.x, f0, f1); unpack2(u0.y, f2, f3);
            a0.x += f0; a0.y += f1; a0.z += f2; a0.w += f3;
            unpack2(u1.x, f0, f1); unpack2(u1.y, f2, f3);
            a1.x += f0; a1.y += f1; a1.z += f2; a1.w += f3;
            unpack2(u2.x, f0, f1); unpack2(u2.y, f2, f3);
            a2.x += f0; a2.y += f1; a2.z += f2; a2.w += f3;
            unpack2(u3.x, f0, f1); unpack2(u3.y, f2, f3);
            a3.x += f0; a3.y += f1; a3.z += f2; a3.w += f3;
        }
        for (; i < len; ++i) {
            const int s = (int)list[start + i];
            const uint2 u = *(const uint2*)(z + (size_t)s * ZP + j4);
            float f0, f1, f2, f3;
            unpack2(u.x, f0, f1); unpack2(u.y, f2, f3);
            a0.x += f0; a0.y += f1; a0.z += f2; a0.w += f3;
        }
        const float inv = 1.0f / (float)max(len, 1);
        const float4 rv = *(const float4*)(r + (size_t)n * ZP + j4);
        sm[g][j4 + 0] = (a0.x + a1.x + a2.x + a3.x) * inv + rv.x;
        sm[g][j4 + 1] = (a0.y + a1.y + a2.y + a3.y) * inv + rv.y;
        sm[g][j4 + 2] = (a0.z + a1.z + a2.z + a3.z) * inv + rv.z;
        sm[g][j4 + 3] = (a0.w + a1.w + a2.w + a3.w) * inv + rv.w;
    }
    __syncthreads();

    if (t < WIN) {
        const int n2 = wb * WIN + t;
        if (n2 < NN) {
            const int sf = *sf_ptr;
            const float* row = sm[t];
            float m = -1e30f;
            for (int c = 0; c < sf; ++c) m = fmaxf(m, row[c]);
            float s = 0.0f;
            for (int c = 0; c < sf; ++c) s += expf(row[c] - m);
            float ls = m + logf(s);
            for (int c = 0; c < sf; ++c)
                out[(long long)n2 * sf + c] = row[c] - ls;
            m = -1e30f;
            for (int c = sf; c < C_OUT; ++c) m = fmaxf(m, row[c]);
            s = 0.0f;
            for (int c = sf; c < C_OUT; ++c) s += expf(row[c] - m);
            ls = m + logf(s);
            const int pt = C_OUT - sf;
            for (int c = sf; c < C_OUT; ++c)
                out[(long long)NN * sf + (long long)n2 * pt + (c - sf)] = row[c] - ls;
        }
    }
}

// ---------------------------------------------------------------------------
extern "C" void kernel_launch(void* const* d_in, const int* in_sizes, int n_in,
                              void* d_out, int out_size, void* d_ws, size_t ws_size,
                              hipStream_t stream)
{
    const float* x   = (const float*)d_in[0];
    const int*   ei  = (const int*)d_in[1];
    const int*   sfp = (const int*)d_in[2];
    const float* W1l = (const float*)d_in[3];
    const float* W1r = (const float*)d_in[4];
    const float* b1  = (const float*)d_in[5];
    const float* W2l = (const float*)d_in[6];
    const float* W2r = (const float*)d_in[7];
    const float* b2  = (const float*)d_in[8];
    float*       out = (float*)d_out;

    const int E = in_sizes[1] / 2;
    const int* src = ei;
    const int* dst = ei + E;

    // ws layout (all 16B-aligned):
    //   dcnt[NWIN*64] | gbase[NWIN*64] | ncur[NWIN*64] | bucket[NWIN*WCAP] |
    //   Wb[32768 us] | W2t[32*128 us] | pqs[NN*128 bf16] | pqa[NN*128 fp8] |
    //   z[NN*16 bf16] | r[NN*16 f32]
    int*      dcnt   = (int*)d_ws;                             // NWIN*64
    int*      gbase  = dcnt + NWIN * WIN;                      // NWIN*64
    int*      ncur   = gbase + NWIN * WIN;                     // NWIN*64
    unsigned* bucket = (unsigned*)(ncur + NWIN * WIN);         // NWIN*WCAP
    unsigned short* Wb  = (unsigned short*)(bucket + (size_t)NWIN * WCAP); // 32768
    unsigned short* W2t = Wb + 2 * 128 * 128;                  // 4096
    unsigned short* pqs = W2t + 32 * 128;                      // NN*128 bf16
    unsigned char*  pqa = (unsigned char*)(pqs + (size_t)NN * 128); // NN*128 fp8
    unsigned short* z   = (unsigned short*)(pqa + (size_t)NN * 128); // NN*16 bf16
    float*          r   = (float*)(z + (size_t)NN * ZP);       // NN*16 fp32

    hipMemsetAsync(dcnt, 0, (size_t)NWIN * WIN * sizeof(int), stream);

    const int binBlocks = (E + EBATCH - 1) / EBATCH;

    // degree count + weight prep (fused, independent roles)
    prepA_kernel<<<binBlocks + WPREPB, 256, 0, stream>>>(
        dst, dcnt, E, binBlocks, W1l, W1r, W2l, W2r, Wb, W2t);

    // per-window exclusive scan -> absolute bases + scatter cursors
    scan_kernel<<<(NWIN + 3) / 4, 256, 0, stream>>>(dcnt, gbase, ncur);

    // scatter edges to exact sorted slots
    prepB_kernel<<<binBlocks, 256, 0, stream>>>(src, dst, ncur, bucket, E);

    // layer-1 GEMM (MFMA, M=64/block, reg-resident B) -> fp8 + bf16 halves
    pre1_kernel<<<(NN + 63) / 64, 256, 0, stream>>>(x, Wb, b1, pqa, pqs);

    // layer-1 aggregation (fp8 gather) + fused layer-2 GEMM -> z, r
    agg1f_kernel<<<NWIN, 256, 0, stream>>>(pqa, pqs, bucket, gbase, dcnt, W2t, b2, z, r);

    // layer-2 aggregation + softmax
    agg2s_kernel<<<NWIN, 256, 0, stream>>>(z, r, bucket, gbase, dcnt, sfp, out);
}

// Round 9
// 218.465 us; speedup vs baseline: 1.9015x; 1.9015x over previous
//
#include <hip/hip_runtime.h>
#include <hip/hip_bf16.h>

#define NN 100000
#define F 128
#define C_OUT 14
#define ZP 16
#define WIN 64
#define NWIN ((NN + WIN - 1) / WIN)    // 1563 windows of 64 nodes
#define WCAP 1408                      // mean 1024, +12 sigma
#define EBATCH 4096
#define HS 136                         // hsm/W2s stride (shorts): 16B-aligned

typedef __attribute__((ext_vector_type(8))) short v8s;   // 8 bf16 (4 VGPRs)
typedef __attribute__((ext_vector_type(4))) float v4f;   // 4 fp32 acc
typedef __attribute__((ext_vector_type(2))) float v2f;   // 2 fp32 (cvt_pk result)

// ---------------- bf16 helpers ----------------------------------------------
static __device__ __forceinline__ unsigned short f2bf(float f) {
    unsigned int u = __float_as_uint(f);
    unsigned int r = (u + 0x7fffu + ((u >> 16) & 1u)) >> 16;   // RTN-even
    return (unsigned short)r;
}
static __device__ __forceinline__ unsigned int pack2(float a, float b) {
    return (unsigned int)f2bf(a) | ((unsigned int)f2bf(b) << 16);
}
static __device__ __forceinline__ void unpack2(unsigned int u, float& lo, float& hi) {
    lo = __uint_as_float(u << 16);
    hi = __uint_as_float(u & 0xffff0000u);
}
// 8 fp8 (uint2) -> accumulate into a[8] via HW converters (2 elems/inst)
static __device__ __forceinline__ void accf8(const uint2 u, float* a) {
    v2f f0 = __builtin_amdgcn_cvt_pk_f32_fp8((int)u.x, false);
    a[0] += f0[0]; a[1] += f0[1];
    v2f f1 = __builtin_amdgcn_cvt_pk_f32_fp8((int)u.x, true);
    a[2] += f1[0]; a[3] += f1[1];
    v2f f2 = __builtin_amdgcn_cvt_pk_f32_fp8((int)u.y, false);
    a[4] += f2[0]; a[5] += f2[1];
    v2f f3 = __builtin_amdgcn_cvt_pk_f32_fp8((int)u.y, true);
    a[6] += f3[0]; a[7] += f3[1];
}
// 4 consecutive bf16 (LDS) -> 4 fp8 packed in one word
static __device__ __forceinline__ unsigned int bf4_to_fp8x4(const unsigned short* sp) {
    float f0, f1, f2, f3;
    unpack2(*(const unsigned int*)(sp + 0), f0, f1);
    unpack2(*(const unsigned int*)(sp + 2), f2, f3);
    unsigned int w = __builtin_amdgcn_cvt_pk_fp8_f32(f0, f1, 0, false);
    return __builtin_amdgcn_cvt_pk_fp8_f32(f2, f3, w, true);
}

// ---------------------------------------------------------------------------
// bin: single pass over edges -> window buckets of 4B entries
// (ent = dloc<<17 | src). Per-block LDS counts, ONE global cursor claim per
// (block,window), CONTIGUOUS range writes (proven R9/R10 -- the R16 scattered
// per-edge variant cost ~200MB of write-allocate HBM traffic; never again).
// ---------------------------------------------------------------------------
__global__ __launch_bounds__(256) void bin_kernel(
    const int* __restrict__ src, const int* __restrict__ dst,
    unsigned* __restrict__ bucket, int* __restrict__ wcur, int E)
{
    __shared__ int cnt_s[NWIN];
    __shared__ int gbase_s[NWIN];
    const int t = threadIdx.x;
    for (int w = t; w < NWIN; w += 256) cnt_s[w] = 0;
    __syncthreads();

    int      wreg[16];
    unsigned ereg[16];
    const int e0 = blockIdx.x * EBATCH;
    #pragma unroll
    for (int j = 0; j < 16; ++j) {
        const int e = e0 + j * 256 + t;
        int w = -1; unsigned ent = 0;
        if (e < E) {
            const int d = dst[e];
            const int s = src[e];
            w   = d >> 6;
            ent = ((unsigned)(d & (WIN - 1)) << 17) | (unsigned)s;
            atomicAdd(&cnt_s[w], 1);
        }
        wreg[j] = w; ereg[j] = ent;
    }
    __syncthreads();
    for (int w = t; w < NWIN; w += 256) {
        const int c = cnt_s[w];
        gbase_s[w] = c ? atomicAdd(&wcur[w], c) : 0;
    }
    __syncthreads();
    for (int w = t; w < NWIN; w += 256) cnt_s[w] = 0;   // reuse as local cursor
    __syncthreads();
    #pragma unroll
    for (int j = 0; j < 16; ++j) {
        const int w = wreg[j];
        if (w >= 0) {
            const int pos = gbase_s[w] + atomicAdd(&cnt_s[w], 1);
            if (pos < WCAP) bucket[(size_t)w * WCAP + pos] = ereg[j];
        }
    }
}

// ---------------------------------------------------------------------------
// wprep: Wb[n][k] = bf16 of [W1l | W1r] transposed, W2t[n][k] = padded W2^T.
// ---------------------------------------------------------------------------
__global__ __launch_bounds__(256) void wprep_kernel(
    const float* __restrict__ W1l, const float* __restrict__ W1r,
    const float* __restrict__ W2l, const float* __restrict__ W2r,
    unsigned short* __restrict__ Wb, unsigned short* __restrict__ W2t)
{
    const int idx = blockIdx.x * 256 + threadIdx.x;
    if (idx < 2 * 128 * 128) {
        const int c   = idx >> 14;
        const int rem = idx & 16383;
        const int n   = rem >> 7;
        const int k   = rem & 127;
        const float* W = c ? W1r : W1l;
        Wb[idx] = f2bf(W[k * 128 + n]);
    } else if (idx < 2 * 128 * 128 + 32 * 128) {
        const int j = idx - 2 * 128 * 128;
        const int n = j >> 7;
        const int k = j & 127;
        float wv = 0.0f;
        if (n < 16) { if (n < C_OUT) wv = W2l[k * C_OUT + n]; }
        else        { if (n - 16 < C_OUT) wv = W2r[k * C_OUT + (n - 16)]; }
        W2t[j] = f2bf(wv);
    }
}

// ---------------------------------------------------------------------------
// pre1 (MFMA): pqa = fp8 of x@W1l [NN][128], pqs = bf16 of x@W1r + b1 [NN][128].
// M=64/block, reg-resident B frags, single-shot A staging (R14 structure).
// ---------------------------------------------------------------------------
#define KSA 136
__global__ __launch_bounds__(256, 3) void pre1_kernel(
    const float* __restrict__ x, const unsigned short* __restrict__ Wb,
    const float* __restrict__ b1, unsigned char* __restrict__ pqa,
    unsigned short* __restrict__ pqs)
{
    __shared__ unsigned short A_s[64 * KSA];   // 17408 B (reused as C_s)

    const int t    = threadIdx.x;
    const int m0   = blockIdx.x * 64;
    const int lane = t & 63;
    const int wave = t >> 6;
    const int lr   = lane & 15;
    const int quad = lane >> 4;
    const int nw0  = wave * 64;

    v8s bf[4][4];
    #pragma unroll
    for (int nt = 0; nt < 4; ++nt)
        #pragma unroll
        for (int ks = 0; ks < 4; ++ks)
            bf[nt][ks] = *(const v8s*)(Wb + (size_t)(nw0 + nt * 16 + lr) * 128 + ks * 32 + quad * 8);

    {
        const int mi = t & 63;
        const int ko = (t >> 6) * 32;
        const int m  = m0 + mi;
        unsigned short* dp = &A_s[mi * KSA + ko];
        if (m < NN) {
            const float4* sp = (const float4*)(x + (size_t)m * F + ko);
            #pragma unroll
            for (int j = 0; j < 8; j += 2) {
                const float4 f0 = sp[j], f1 = sp[j + 1];
                uint4 o;
                o.x = pack2(f0.x, f0.y); o.y = pack2(f0.z, f0.w);
                o.z = pack2(f1.x, f1.y); o.w = pack2(f1.z, f1.w);
                *(uint4*)(dp + j * 4) = o;
            }
        } else {
            #pragma unroll
            for (int j = 0; j < 4; ++j)
                *(uint4*)(dp + j * 8) = make_uint4(0u, 0u, 0u, 0u);
        }
    }
    __syncthreads();

    v4f acc[4][4];
    #pragma unroll
    for (int mt = 0; mt < 4; ++mt)
        #pragma unroll
        for (int nt = 0; nt < 4; ++nt)
            acc[mt][nt] = (v4f){0.f, 0.f, 0.f, 0.f};

    #pragma unroll
    for (int ks = 0; ks < 4; ++ks) {
        const int k0 = ks * 32 + quad * 8;
        #pragma unroll
        for (int mt = 0; mt < 4; ++mt) {
            const v8s a = *(const v8s*)&A_s[(mt * 16 + lr) * KSA + k0];
            acc[mt][0] = __builtin_amdgcn_mfma_f32_16x16x32_bf16(a, bf[0][ks], acc[mt][0], 0, 0, 0);
            acc[mt][1] = __builtin_amdgcn_mfma_f32_16x16x32_bf16(a, bf[1][ks], acc[mt][1], 0, 0, 0);
            acc[mt][2] = __builtin_amdgcn_mfma_f32_16x16x32_bf16(a, bf[2][ks], acc[mt][2], 0, 0, 0);
            acc[mt][3] = __builtin_amdgcn_mfma_f32_16x16x32_bf16(a, bf[3][ks], acc[mt][3], 0, 0, 0);
        }
    }
    __syncthreads();

    float bias[4];
    #pragma unroll
    for (int nt = 0; nt < 4; ++nt) {
        const int n = nw0 + nt * 16 + lr;
        bias[nt] = (n >= 128) ? b1[n - 128] : 0.0f;
    }

    unsigned short* C_s = A_s;
    #pragma unroll
    for (int p = 0; p < 2; ++p) {
        if ((nw0 >> 7) == p) {
            #pragma unroll
            for (int mt = 0; mt < 4; ++mt)
                #pragma unroll
                for (int nt = 0; nt < 4; ++nt) {
                    const int n = (nw0 & 127) + nt * 16 + lr;
                    #pragma unroll
                    for (int r = 0; r < 4; ++r) {
                        const int m = mt * 16 + quad * 4 + r;
                        C_s[m * KSA + n] = f2bf(acc[mt][nt][r] + bias[nt]);
                    }
                }
        }
        __syncthreads();
        if (p == 0) {
            const int mi8 = t >> 2;
            const int c0  = (t & 3) * 32;
            const int m   = m0 + mi8;
            if (m < NN) {
                unsigned char* dp = pqa + (size_t)m * 128 + c0;
                #pragma unroll
                for (int j = 0; j < 2; ++j) {
                    const unsigned short* sp = &C_s[mi8 * KSA + c0 + j * 16];
                    uint4 w;
                    w.x = bf4_to_fp8x4(sp + 0);
                    w.y = bf4_to_fp8x4(sp + 4);
                    w.z = bf4_to_fp8x4(sp + 8);
                    w.w = bf4_to_fp8x4(sp + 12);
                    *(uint4*)(dp + j * 16) = w;
                }
            }
        } else {
            const int mi = t >> 2;
            const int c0 = (t & 3) * 32;
            const int m  = m0 + mi;
            if (m < NN) {
                unsigned short* dp = pqs + (size_t)m * 128 + c0;
                const unsigned short* sp = &C_s[mi * KSA + c0];
                #pragma unroll
                for (int j = 0; j < 4; ++j)
                    *(uint4*)(dp + j * 8) = *(const uint4*)(sp + j * 8);
            }
        }
        __syncthreads();
    }
}

// ---------------------------------------------------------------------------
// agg1f: window-local CSR sort + fp8 register gather, pre2 fused (MFMA).
// (R13/R14 proven structure: LDS sort, unroll-8 gather, sorted-CSR export)
// ---------------------------------------------------------------------------
__global__ __launch_bounds__(256, 5) void agg1f_kernel(
    const unsigned char* __restrict__ pqa, const unsigned short* __restrict__ pqs,
    unsigned* __restrict__ bucket, const int* __restrict__ wcur,
    const unsigned short* __restrict__ W2t, const float* __restrict__ b2,
    int* __restrict__ wbase, unsigned short* __restrict__ z, float* __restrict__ r)
{
    __shared__ unsigned list[WCAP];                 // 5632 B
    __shared__ int cnt_s[WIN], base_s[WIN], cur_s[WIN];  // 768 B
    __shared__ unsigned short hsm[WIN * HS];        // 17408 B
    __shared__ unsigned short W2s[32 * HS];         // 8704 B   (total 32512)
    const int t  = threadIdx.x;
    const int wb = blockIdx.x;
    const int cntw = min(wcur[wb], WCAP);
    unsigned* bp = bucket + (size_t)wb * WCAP;

    {
        const int row = t >> 3;
        const int c16 = (t & 7) * 16;
        *(uint4*)&W2s[row * HS + c16]     = *(const uint4*)&W2t[row * 128 + c16];
        *(uint4*)&W2s[row * HS + c16 + 8] = *(const uint4*)&W2t[row * 128 + c16 + 8];
    }

    if (t < WIN) cnt_s[t] = 0;
    __syncthreads();
    for (int i = t; i < cntw; i += 256) atomicAdd(&cnt_s[bp[i] >> 17], 1);
    __syncthreads();
    if (t < WIN) base_s[t] = cnt_s[t];
    __syncthreads();
    for (int off = 1; off < WIN; off <<= 1) {
        int v = 0;
        if (t < WIN && t >= off) v = base_s[t - off];
        __syncthreads();
        if (t < WIN) base_s[t] += v;
        __syncthreads();
    }
    if (t < WIN) { const int b = base_s[t] - cnt_s[t]; base_s[t] = b; cur_s[t] = b; }
    __syncthreads();
    for (int i = t; i < cntw; i += 256) {
        const unsigned e = bp[i];                   // L2-hot re-read
        list[atomicAdd(&cur_s[e >> 17], 1)] = e & 0x1FFFFu;
    }
    __syncthreads();

    // export sorted CSR for agg2s
    for (int i = t; i < cntw; i += 256) bp[i] = list[i];
    if (t < WIN) wbase[wb * WIN + t] = base_s[t];

    const int g    = t >> 4;      // 16 groups
    const int lane = t & 15;
    const int col  = lane * 8;    // byte offset into the 128B fp8 row
    #pragma unroll
    for (int rep = 0; rep < 4; ++rep) {
        const int nloc = rep * 16 + g;
        const int n = wb * WIN + nloc;
        if (n >= NN) continue;
        const int start = base_s[nloc];
        const int len   = cnt_s[nloc];
        float a0[8] = {0,0,0,0,0,0,0,0};
        float a1[8] = {0,0,0,0,0,0,0,0};
        float a2[8] = {0,0,0,0,0,0,0,0};
        float a3[8] = {0,0,0,0,0,0,0,0};
        int i = 0;
        for (; i + 8 <= len; i += 8) {
            const int s0 = (int)list[start + i + 0];
            const int s1 = (int)list[start + i + 1];
            const int s2 = (int)list[start + i + 2];
            const int s3 = (int)list[start + i + 3];
            const int s4 = (int)list[start + i + 4];
            const int s5 = (int)list[start + i + 5];
            const int s6 = (int)list[start + i + 6];
            const int s7 = (int)list[start + i + 7];
            const uint2 u0 = *(const uint2*)(pqa + (size_t)s0 * 128 + col);
            const uint2 u1 = *(const uint2*)(pqa + (size_t)s1 * 128 + col);
            const uint2 u2 = *(const uint2*)(pqa + (size_t)s2 * 128 + col);
            const uint2 u3 = *(const uint2*)(pqa + (size_t)s3 * 128 + col);
            const uint2 u4 = *(const uint2*)(pqa + (size_t)s4 * 128 + col);
            const uint2 u5 = *(const uint2*)(pqa + (size_t)s5 * 128 + col);
            const uint2 u6 = *(const uint2*)(pqa + (size_t)s6 * 128 + col);
            const uint2 u7 = *(const uint2*)(pqa + (size_t)s7 * 128 + col);
            accf8(u0, a0); accf8(u1, a1); accf8(u2, a2); accf8(u3, a3);
            accf8(u4, a0); accf8(u5, a1); accf8(u6, a2); accf8(u7, a3);
        }
        for (; i + 4 <= len; i += 4) {
            const int s0 = (int)list[start + i + 0];
            const int s1 = (int)list[start + i + 1];
            const int s2 = (int)list[start + i + 2];
            const int s3 = (int)list[start + i + 3];
            const uint2 u0 = *(const uint2*)(pqa + (size_t)s0 * 128 + col);
            const uint2 u1 = *(const uint2*)(pqa + (size_t)s1 * 128 + col);
            const uint2 u2 = *(const uint2*)(pqa + (size_t)s2 * 128 + col);
            const uint2 u3 = *(const uint2*)(pqa + (size_t)s3 * 128 + col);
            accf8(u0, a0); accf8(u1, a1); accf8(u2, a2); accf8(u3, a3);
        }
        for (; i < len; ++i) {
            const int s = (int)list[start + i];
            const uint2 u = *(const uint2*)(pqa + (size_t)s * 128 + col);
            accf8(u, a0);
        }
        const float inv = 1.0f / (float)max(len, 1);
        const uint4 uq = *(const uint4*)(pqs + (size_t)n * 128 + lane * 8);
        float q[8];
        unpack2(uq.x, q[0], q[1]); unpack2(uq.y, q[2], q[3]);
        unpack2(uq.z, q[4], q[5]); unpack2(uq.w, q[6], q[7]);
        float hv[8];
        #pragma unroll
        for (int j = 0; j < 8; ++j)
            hv[j] = fmaxf((a0[j] + a1[j] + a2[j] + a3[j]) * inv + q[j], 0.0f);
        uint4 o;
        o.x = pack2(hv[0], hv[1]);
        o.y = pack2(hv[2], hv[3]);
        o.z = pack2(hv[4], hv[5]);
        o.w = pack2(hv[6], hv[7]);
        *(uint4*)&hsm[nloc * HS + lane * 8] = o;
    }
    __syncthreads();

    // fused pre2 via MFMA: [z|r](64x32) = h(64x128) @ W2t^T.
    {
        const int wave = t >> 6;
        const int l64  = t & 63;
        const int lr   = l64 & 15;
        const int quad = l64 >> 4;
        const int m0w  = wave * 16;
        v4f accz = (v4f){0.f, 0.f, 0.f, 0.f};
        v4f accr = (v4f){0.f, 0.f, 0.f, 0.f};
        #pragma unroll
        for (int kt = 0; kt < 4; ++kt) {
            const int k0 = kt * 32 + quad * 8;
            const v8s a  = *(const v8s*)&hsm[(m0w + lr) * HS + k0];
            const v8s bz = *(const v8s*)&W2s[lr * HS + k0];
            const v8s br = *(const v8s*)&W2s[(16 + lr) * HS + k0];
            accz = __builtin_amdgcn_mfma_f32_16x16x32_bf16(a, bz, accz, 0, 0, 0);
            accr = __builtin_amdgcn_mfma_f32_16x16x32_bf16(a, br, accr, 0, 0, 0);
        }
        const float b2v = (lr < C_OUT) ? b2[lr] : 0.0f;
        #pragma unroll
        for (int rr = 0; rr < 4; ++rr) {
            const int m = m0w + quad * 4 + rr;
            const int n = wb * WIN + m;
            if (n < NN) {
                z[(size_t)n * ZP + lr] = f2bf(accz[rr]);
                r[(size_t)n * ZP + lr] = accr[rr] + b2v;
            }
        }
    }
}

// ---------------------------------------------------------------------------
// agg2s: consumes the PRE-SORTED CSR from agg1f (unroll-8 gather).
// ---------------------------------------------------------------------------
__global__ __launch_bounds__(256) void agg2s_kernel(
    const unsigned short* __restrict__ z, const float* __restrict__ r,
    const unsigned* __restrict__ bucket, const int* __restrict__ wcur,
    const int* __restrict__ wbase, const int* __restrict__ sf_ptr,
    float* __restrict__ out)
{
    __shared__ unsigned list[WCAP];
    __shared__ int base_s[WIN + 1];
    __shared__ float sm[WIN][ZP + 1];
    const int t  = threadIdx.x;
    const int wb = blockIdx.x;
    const int cntw = min(wcur[wb], WCAP);
    const unsigned* bp = bucket + (size_t)wb * WCAP;

    if (t < WIN) base_s[t] = wbase[wb * WIN + t];
    if (t == 0) base_s[WIN] = cntw;
    for (int i = t; i < cntw; i += 256) list[i] = bp[i];
    __syncthreads();

    const int g  = t >> 2;      // node slot 0..63
    const int j4 = (t & 3) * 4;
    const int n  = wb * WIN + g;
    if (n < NN) {
        const int start = base_s[g];
        const int len   = base_s[g + 1] - base_s[g];
        float4 a0 = make_float4(0.f, 0.f, 0.f, 0.f);
        float4 a1 = a0, a2 = a0, a3 = a0;
        int i = 0;
        for (; i + 8 <= len; i += 8) {
            const int s0 = (int)list[start + i + 0];
            const int s1 = (int)list[start + i + 1];
            const int s2 = (int)list[start + i + 2];
            const int s3 = (int)list[start + i + 3];
            const int s4 = (int)list[start + i + 4];
            const int s5 = (int)list[start + i + 5];
            const int s6 = (int)list[start + i + 6];
            const int s7 = (int)list[start + i + 7];
            const uint2 u0 = *(const uint2*)(z + (size_t)s0 * ZP + j4);
            const uint2 u1 = *(const uint2*)(z + (size_t)s1 * ZP + j4);
            const uint2 u2 = *(const uint2*)(z + (size_t)s2 * ZP + j4);
            const uint2 u3 = *(const uint2*)(z + (size_t)s3 * ZP + j4);
            const uint2 u4 = *(const uint2*)(z + (size_t)s4 * ZP + j4);
            const uint2 u5 = *(const uint2*)(z + (size_t)s5 * ZP + j4);
            const uint2 u6 = *(const uint2*)(z + (size_t)s6 * ZP + j4);
            const uint2 u7 = *(const uint2*)(z + (size_t)s7 * ZP + j4);
            float f0, f1, f2, f3;
            unpack2(u0.x, f0, f1); unpack2(u0.y, f2, f3);
            a0.x += f0; a0.y += f1; a0.z += f2; a0.w += f3;
            unpack2(u1.x, f0, f1); unpack2(u1.y, f2, f3);
            a1.x += f0; a1.y += f1; a1.z += f2; a1.w += f3;
            unpack2(u2.x, f0, f1); unpack2(u2.y, f2, f3);
            a2.x += f0; a2.y += f1; a2.z += f2; a2.w += f3;
            unpack2(u3.x, f0, f1); unpack2(u3.y, f2, f3);
            a3.x += f0; a3.y += f1; a3.z += f2; a3.w += f3;
            unpack2(u4.x, f0, f1); unpack2(u4.y, f2, f3);
            a0.x += f0; a0.y += f1; a0.z += f2; a0.w += f3;
            unpack2(u5.x, f0, f1); unpack2(u5.y, f2, f3);
            a1.x += f0; a1.y += f1; a1.z += f2; a1.w += f3;
            unpack2(u6.x, f0, f1); unpack2(u6.y, f2, f3);
            a2.x += f0; a2.y += f1; a2.z += f2; a2.w += f3;
            unpack2(u7.x, f0, f1); unpack2(u7.y, f2, f3);
            a3.x += f0; a3.y += f1; a3.z += f2; a3.w += f3;
        }
        for (; i + 4 <= len; i += 4) {
            const int s0 = (int)list[start + i + 0];
            const int s1 = (int)list[start + i + 1];
            const int s2 = (int)list[start + i + 2];
            const int s3 = (int)list[start + i + 3];
            const uint2 u0 = *(const uint2*)(z + (size_t)s0 * ZP + j4);
            const uint2 u1 = *(const uint2*)(z + (size_t)s1 * ZP + j4);
            const uint2 u2 = *(const uint2*)(z + (size_t)s2 * ZP + j4);
            const uint2 u3 = *(const uint2*)(z + (size_t)s3 * ZP + j4);
            float f0, f1, f2, f3;
            unpack2(u0.x, f0, f1); unpack2(u0.y, f2, f3);
            a0.x += f0; a0.y += f1; a0.z += f2; a0.w += f3;
            unpack2(u1.x, f0, f1); unpack2(u1.y, f2, f3);
            a1.x += f0; a1.y += f1; a1.z += f2; a1.w += f3;
            unpack2(u2.x, f0, f1); unpack2(u2.y, f2, f3);
            a2.x += f0; a2.y += f1; a2.z += f2; a2.w += f3;
            unpack2(u3.x, f0, f1); unpack2(u3.y, f2, f3);
            a3.x += f0; a3.y += f1; a3.z += f2; a3.w += f3;
        }
        for (; i < len; ++i) {
            const int s = (int)list[start + i];
            const uint2 u = *(const uint2*)(z + (size_t)s * ZP + j4);
            float f0, f1, f2, f3;
            unpack2(u.x, f0, f1); unpack2(u.y, f2, f3);
            a0.x += f0; a0.y += f1; a0.z += f2; a0.w += f3;
        }
        const float inv = 1.0f / (float)max(len, 1);
        const float4 rv = *(const float4*)(r + (size_t)n * ZP + j4);
        sm[g][j4 + 0] = (a0.x + a1.x + a2.x + a3.x) * inv + rv.x;
        sm[g][j4 + 1] = (a0.y + a1.y + a2.y + a3.y) * inv + rv.y;
        sm[g][j4 + 2] = (a0.z + a1.z + a2.z + a3.z) * inv + rv.z;
        sm[g][j4 + 3] = (a0.w + a1.w + a2.w + a3.w) * inv + rv.w;
    }
    __syncthreads();

    if (t < WIN) {
        const int n2 = wb * WIN + t;
        if (n2 < NN) {
            const int sf = *sf_ptr;
            const float* row = sm[t];
            float m = -1e30f;
            for (int c = 0; c < sf; ++c) m = fmaxf(m, row[c]);
            float s = 0.0f;
            for (int c = 0; c < sf; ++c) s += expf(row[c] - m);
            float ls = m + logf(s);
            for (int c = 0; c < sf; ++c)
                out[(long long)n2 * sf + c] = row[c] - ls;
            m = -1e30f;
            for (int c = sf; c < C_OUT; ++c) m = fmaxf(m, row[c]);
            s = 0.0f;
            for (int c = sf; c < C_OUT; ++c) s += expf(row[c] - m);
            ls = m + logf(s);
            const int pt = C_OUT - sf;
            for (int c = sf; c < C_OUT; ++c)
                out[(long long)NN * sf + (long long)n2 * pt + (c - sf)] = row[c] - ls;
        }
    }
}

// ---------------------------------------------------------------------------
extern "C" void kernel_launch(void* const* d_in, const int* in_sizes, int n_in,
                              void* d_out, int out_size, void* d_ws, size_t ws_size,
                              hipStream_t stream)
{
    const float* x   = (const float*)d_in[0];
    const int*   ei  = (const int*)d_in[1];
    const int*   sfp = (const int*)d_in[2];
    const float* W1l = (const float*)d_in[3];
    const float* W1r = (const float*)d_in[4];
    const float* b1  = (const float*)d_in[5];
    const float* W2l = (const float*)d_in[6];
    const float* W2r = (const float*)d_in[7];
    const float* b2  = (const float*)d_in[8];
    float*       out = (float*)d_out;

    const int E = in_sizes[1] / 2;
    const int* src = ei;
    const int* dst = ei + E;

    // ws layout (all 16B-aligned):
    //   wcur[2048] | wbase[NWIN*64] | bucket[NWIN*WCAP] | Wb[32768 us] |
    //   W2t[32*128 us] | pqs[NN*128 bf16] | pqa[NN*128 fp8] | z[NN*16 bf16] | r[NN*16 f32]
    int*      wcur   = (int*)d_ws;                             // 2048
    int*      wbase  = wcur + 2048;                            // NWIN*64
    unsigned* bucket = (unsigned*)(wbase + NWIN * WIN);        // NWIN*WCAP
    unsigned short* Wb  = (unsigned short*)(bucket + (size_t)NWIN * WCAP); // 32768
    unsigned short* W2t = Wb + 2 * 128 * 128;                  // 4096
    unsigned short* pqs = W2t + 32 * 128;                      // NN*128 bf16
    unsigned char*  pqa = (unsigned char*)(pqs + (size_t)NN * 128); // NN*128 fp8
    unsigned short* z   = (unsigned short*)(pqa + (size_t)NN * 128); // NN*16 bf16
    float*          r   = (float*)(z + (size_t)NN * ZP);       // NN*16 fp32

    hipMemsetAsync(wcur, 0, 2048 * sizeof(int), stream);

    // edge binning into 64-node windows (contiguous-range writes)
    bin_kernel<<<(E + EBATCH - 1) / EBATCH, 256, 0, stream>>>(src, dst, bucket, wcur, E);

    // weight prep (W1 transposed bf16 + W2 transposed/padded bf16)
    wprep_kernel<<<(2 * 128 * 128 + 32 * 128 + 255) / 256, 256, 0, stream>>>(
        W1l, W1r, W2l, W2r, Wb, W2t);

    // layer-1 GEMM (MFMA, M=64/block, reg-resident B) -> fp8 + bf16 halves
    pre1_kernel<<<(NN + 63) / 64, 256, 0, stream>>>(x, Wb, b1, pqa, pqs);

    // layer-1 aggregation (fp8 gather) + fused layer-2 GEMM (MFMA) -> z, r
    agg1f_kernel<<<NWIN, 256, 0, stream>>>(pqa, pqs, bucket, wcur, W2t, b2, wbase, z, r);

    // layer-2 aggregation + softmax (consumes sorted CSR)
    agg2s_kernel<<<NWIN, 256, 0, stream>>>(z, r, bucket, wcur, wbase, sfp, out);
}